// Round 4
// baseline (145.197 us; speedup 1.0000x reference)
//
#include <hip/hip_runtime.h>
#include <hip/hip_bf16.h>

typedef __attribute__((ext_vector_type(8)))  short bf16x8;
typedef __attribute__((ext_vector_type(4)))  short short4v;
typedef __attribute__((ext_vector_type(16))) float f32x16;

constexpr int SQ = 2048;
constexpr int NB = 2;
constexpr int NH = 16;
constexpr int D  = 64;
constexpr int SROW = NB * NH * D;        // 2048 floats per s step (layout s,b,h,d)
constexpr int BH   = NB * NH;            // 32 (b,h) planes
constexpr int LDP = 72;                  // cvt LDS leading dim (shorts, 144B = b128-aligned)
constexpr int PST = 68;                  // P row stride (136 B -> 2-way banks, 8B-aligned)
constexpr int TCH = 4096;                // shorts per 64x64 bf16 tile
constexpr size_t PLANE = (size_t)SQ * D; // 131072 shorts per (b,h) plane

// scale folded into Q: 1/sqrt(64) (coeff cancels) * log2(e) so exp2() is direct
constexpr float QSCALE = 0.125f * 1.44269504088896f;

// pack two fp32 -> bf16x2 dword (round-half-up; differs from RNE only on ties)
__device__ __forceinline__ int pack2(float lo, float hi) {
    unsigned ul = __builtin_bit_cast(unsigned, lo) + 0x8000u;
    unsigned uh = __builtin_bit_cast(unsigned, hi) + 0x8000u;
    return __builtin_amdgcn_perm(uh, ul, 0x07060302);  // {hi.b3,hi.b2,lo.b3,lo.b2}
}

__device__ __forceinline__ f32x16 z16() {
    f32x16 z;
    #pragma unroll
    for (int i = 0; i < 16; ++i) z[i] = 0.f;
    return z;
}

// ---------------------------------------------------------------------------
// Pre-kernel v2: K, V fp32 -> bf16 in 32x32x16-MFMA fragment order.
// BOTH arrays staged through LDS with fully coalesced float4 global reads
// (old K path issued 64 x 32B scattered reads per wave -> suspected large
// hidden cost), then fragments emitted as coalesced int4 global stores.
//   Per 64x64 tile, 8 fragments (f) of 64 lanes x 16 B:
//   K frag f=(nt*4+ks), lane l: K[nt*32+(l&31)][ks*16+(l>>5)*8 ..+7]
//   V frag f=(dt*4+ts), lane l: V^T[dt*32+(l&31)][ts*16+(l>>5)*8 ..+7]
// ---------------------------------------------------------------------------
__global__ __launch_bounds__(256)
void cvt(const float* __restrict__ K, const float* __restrict__ V,
         short* __restrict__ Kf, short* __restrict__ Vf) {
    __shared__ short Kl[64][LDP];
    __shared__ short Vl[64][LDP];
    const int tid  = threadIdx.x;
    const int tile = blockIdx.x;
    const int bh   = blockIdx.y;
    const int t0   = tile * 64;

    {   // stage K and V tiles into LDS bf16, coalesced fp32 reads
        const int r = tid >> 2, c = (tid & 3) * 16;
        const float* kp = K + (size_t)(t0 + r) * SROW + bh * D + c;
        const float* vp = V + (size_t)(t0 + r) * SROW + bh * D + c;
        int ok[8], ov[8];
        #pragma unroll
        for (int i = 0; i < 8; ++i) {
            ok[i] = pack2(kp[2 * i], kp[2 * i + 1]);
            ov[i] = pack2(vp[2 * i], vp[2 * i + 1]);
        }
        *(int4*)&Kl[r][c]     = *(int4*)&ok[0];
        *(int4*)&Kl[r][c + 8] = *(int4*)&ok[4];
        *(int4*)&Vl[r][c]     = *(int4*)&ov[0];
        *(int4*)&Vl[r][c + 8] = *(int4*)&ov[4];
    }
    __syncthreads();

    short* kout = Kf + (size_t)bh * PLANE + (size_t)tile * TCH;
    short* vout = Vf + (size_t)bh * PLANE + (size_t)tile * TCH;
    #pragma unroll
    for (int cc = tid; cc < 512; cc += 256) {
        const int f  = cc >> 6, ln = cc & 63, hi = ln >> 5;
        {   // K fragment: aligned b128 LDS read (row stride 144 B)
            const int nt = f >> 2, ks = f & 3;
            const int row = nt * 32 + (ln & 31);
            const int col = ks * 16 + hi * 8;
            *(int4*)&kout[cc * 8] = *(const int4*)&Kl[row][col];
        }
        {   // V^T fragment via LDS transpose gather
            const int dt = f >> 2, ts = f & 3;
            const int d  = dt * 32 + (ln & 31);
            short t8[8];
            #pragma unroll
            for (int j = 0; j < 8; ++j) t8[j] = Vl[ts * 16 + hi * 8 + j][d];
            *(int4*)&vout[cc * 8] = *(int4*)t8;
        }
    }
}

// ---------------------------------------------------------------------------
// Hot kernel v5: 32x32 MFMA causal flash attention.
//  R3 post-mortem: all prior variants were fragment-read-bandwidth bound
//  (each wave re-read 16 KB K/V per tile-iter for only 16 q-rows; ~26 us of
//  pure pipe time per CU). Fix: mfma_f32_32x32x16_bf16 -> 32 q-rows per wave
//  per tile read, HALVING fragment traffic per unit work.
//  - Block = 4 waves x 32 q = 128-row strip. 512 blocks; CU c hosts strips
//    {15-u, u} (g=0 long first) = constant 34 block-iters/CU; bh = c&31
//    keeps bh%8 == XCD id.
//  - K/V fragments read straight from global/L1 (v1-verified path; 16 KB
//    tile fits L1; DS pipe carries only P). No barriers anywhere.
//  - S^T (D: col=lane&31=q, row=(r&3)+8*(r>>2)+4*hi=t [m101-verified]) goes
//    through the verified per-wave LDS P buffer: b64 writes at t =
//    nt*32+4*hi+{0,8,16,24}, b64-pair reads at t = ts*16+hi*8 -> PV A-frags.
//  - l = mfma(pa, ones) -> same reg layout as O (v1-verified idiom).
//  - launch_bounds(256,2): 2 blocks/CU, VGPR cap 256 so kf/vf prefetch can
//    stay resident (R2 failed with cap 128).
// ---------------------------------------------------------------------------
__global__ __launch_bounds__(256, 2)
void attn_fwd(const float* __restrict__ Q, const short* __restrict__ Kf,
              const short* __restrict__ Vf, float* __restrict__ Out) {
    __shared__ short Pls[4][32][PST];   // [wave][q][t] bf16, per-wave private

    const int tid  = threadIdx.x;
    const int wave = tid >> 6;
    const int lane = tid & 63;
    const int q32  = lane & 31;
    const int hi   = lane >> 5;

    const int c  = blockIdx.x & 255;
    const int g  = blockIdx.x >> 8;
    const int u  = c >> 5;              // 0..7
    const int bh = c & 31;
    const int a  = g ? u : (15 - u);    // strip128 id, long strips first
    const int s  = 2 * a + (wave >> 1); // last tile index for this wave
    const int limit = 32 * (wave & 1) + q32;  // causal t-limit in diag tile

    const short* kb = Kf + (size_t)bh * PLANE;
    const short* vb = Vf + (size_t)bh * PLANE;
    auto ldK = [&](int t, int f) -> bf16x8 {
        return *(const bf16x8*)(kb + (size_t)t * TCH + f * 512 + lane * 8);
    };
    auto ldV = [&](int t, int f) -> bf16x8 {
        return *(const bf16x8*)(vb + (size_t)t * TCH + f * 512 + lane * 8);
    };

    // prologue: fragments for tile 0
    bf16x8 kf[8], vf[8];
    #pragma unroll
    for (int j = 0; j < 8; ++j) { kf[j] = ldK(0, j); vf[j] = ldV(0, j); }

    // ---- Q B-fragments: lane holds Q[qrow][ks*16 + hi*8 ..+7], scaled ----
    bf16x8 qf[4];
    {
        const int qrow = a * 128 + wave * 32 + q32;
        const float* qp = Q + (size_t)qrow * SROW + bh * D + hi * 8;
        #pragma unroll
        for (int ks = 0; ks < 4; ++ks) {
            float4 x0 = *(const float4*)(qp + ks * 16);
            float4 x1 = *(const float4*)(qp + ks * 16 + 4);
            int o4[4];
            o4[0] = pack2(x0.x * QSCALE, x0.y * QSCALE);
            o4[1] = pack2(x0.z * QSCALE, x0.w * QSCALE);
            o4[2] = pack2(x1.x * QSCALE, x1.y * QSCALE);
            o4[3] = pack2(x1.z * QSCALE, x1.w * QSCALE);
            qf[ks] = *(bf16x8*)o4;
        }
    }

    f32x16 o0 = z16(), o1 = z16(), l = z16();
    bf16x8 ones;
    #pragma unroll
    for (int i = 0; i < 8; ++i) ones[i] = (short)0x3F80;  // bf16 1.0

    for (int it = 0; it <= s; ++it) {
        // ---- S^T = K Q^T (two 32x32 t-tiles, K-dim 64 in 4 steps) ----
        f32x16 sA = z16(), sB = z16();
        #pragma unroll
        for (int ks = 0; ks < 4; ++ks)
            sA = __builtin_amdgcn_mfma_f32_32x32x16_bf16(kf[ks],     qf[ks], sA, 0, 0, 0);
        #pragma unroll
        for (int ks = 0; ks < 4; ++ks)
            sB = __builtin_amdgcn_mfma_f32_32x32x16_bf16(kf[4 + ks], qf[ks], sB, 0, 0, 0);

        // ---- prefetch K fragments for next tile (clamped, branchless) ----
        const int nx = (it < s) ? it + 1 : s;
        #pragma unroll
        for (int j = 0; j < 8; ++j) kf[j] = ldK(nx, j);

        // ---- exp2 + pack + P->LDS (per-wave buffer, in-wave ordering) ----
        const bool diag = (it == s);
        #pragma unroll
        for (int nt = 0; nt < 2; ++nt) {
            const f32x16& sN = nt ? sB : sA;
            float e[16];
            #pragma unroll
            for (int r = 0; r < 16; ++r) {
                const int tl = nt * 32 + (r & 3) + 8 * (r >> 2) + 4 * hi;
                float xv = sN[r];
                if (diag && tl > limit) xv = -1e30f;
                e[r] = __builtin_exp2f(xv);
            }
            int pdw[8];
            #pragma unroll
            for (int d8 = 0; d8 < 8; ++d8) pdw[d8] = pack2(e[2 * d8], e[2 * d8 + 1]);
            short* prow = &Pls[wave][q32][nt * 32 + 4 * hi];
            *(int2*)(prow)      = make_int2(pdw[0], pdw[1]);   // t +0..3
            *(int2*)(prow + 8)  = make_int2(pdw[2], pdw[3]);   // t +8..11
            *(int2*)(prow + 16) = make_int2(pdw[4], pdw[5]);   // t +16..19
            *(int2*)(prow + 24) = make_int2(pdw[6], pdw[7]);   // t +24..27
        }

        // ---- O += P V ; l += P*1 (A-frag: P[q32][ts*16 + hi*8 ..+7]) ----
        #pragma unroll
        for (int ts = 0; ts < 4; ++ts) {
            const short* pb = &Pls[wave][q32][ts * 16 + hi * 8];
            bf16x8 pa;
            *(short4v*)&pa       = *(const short4v*)pb;
            *((short4v*)&pa + 1) = *(const short4v*)(pb + 4);
            l  = __builtin_amdgcn_mfma_f32_32x32x16_bf16(pa, ones,        l,  0, 0, 0);
            o0 = __builtin_amdgcn_mfma_f32_32x32x16_bf16(pa, vf[ts],      o0, 0, 0, 0);
            o1 = __builtin_amdgcn_mfma_f32_32x32x16_bf16(pa, vf[4 + ts],  o1, 0, 0, 0);
        }

        // ---- prefetch V fragments for next tile ----
        #pragma unroll
        for (int j = 0; j < 8; ++j) vf[j] = ldV(nx, j);
    }

    // ---- epilogue: normalize, store fp32 (lane = one d column, 16 q rows) ----
    #pragma unroll
    for (int r = 0; r < 16; ++r) {
        const int qr   = (r & 3) + 8 * (r >> 2) + 4 * hi;
        const float inv = 1.f / l[r];
        float* op = Out + (size_t)(a * 128 + wave * 32 + qr) * SROW + bh * D;
        op[q32]      = o0[r] * inv;
        op[32 + q32] = o1[r] * inv;
    }
}

extern "C" void kernel_launch(void* const* d_in, const int* in_sizes, int n_in,
                              void* d_out, int out_size, void* d_ws, size_t ws_size,
                              hipStream_t stream) {
    const float* Q = (const float*)d_in[0];
    const float* K = (const float*)d_in[1];
    const float* V = (const float*)d_in[2];
    // d_in[3] (attention_mask) is pure causal — folded into the kernel.
    float* Out = (float*)d_out;

    // d_ws layout: Kf | Vf (bf16, fragment order), 8 MB each
    short* Kf = (short*)d_ws;
    short* Vf = Kf + (size_t)BH * PLANE;

    dim3 gcvt(SQ / 64, BH);
    cvt<<<gcvt, 256, 0, stream>>>(K, V, Kf, Vf);
    attn_fwd<<<dim3(512), 256, 0, stream>>>(Q, Kf, Vf, Out);
}

// Round 5
// 141.551 us; speedup vs baseline: 1.0258x; 1.0258x over previous
//
#include <hip/hip_runtime.h>
#include <hip/hip_bf16.h>

typedef __attribute__((ext_vector_type(8)))  short bf16x8;
typedef __attribute__((ext_vector_type(16))) float f32x16;

constexpr int SQ = 2048;
constexpr int NB = 2;
constexpr int NH = 16;
constexpr int D  = 64;
constexpr int SROW = NB * NH * D;        // 2048 floats per s step (layout s,b,h,d)
constexpr int BH   = NB * NH;            // 32 (b,h) planes
constexpr int LDP = 72;                  // cvt LDS leading dim (shorts, 144B = b128-aligned)
constexpr int TCH = 4096;                // shorts per 64x64 bf16 tile
constexpr size_t PLANE = (size_t)SQ * D; // 131072 shorts per (b,h) plane

// scale folded into Q: 1/sqrt(64) (coeff cancels) * log2(e) so exp2() is direct
constexpr float QSCALE = 0.125f * 1.44269504088896f;

// pack two fp32 -> bf16x2 dword (round-half-up; differs from RNE only on ties)
__device__ __forceinline__ int pack2(float lo, float hi) {
    unsigned ul = __builtin_bit_cast(unsigned, lo) + 0x8000u;
    unsigned uh = __builtin_bit_cast(unsigned, hi) + 0x8000u;
    return __builtin_amdgcn_perm(uh, ul, 0x07060302);  // {hi.b3,hi.b2,lo.b3,lo.b2}
}

__device__ __forceinline__ f32x16 z16() {
    f32x16 z;
    #pragma unroll
    for (int i = 0; i < 16; ++i) z[i] = 0.f;
    return z;
}

// ---------------------------------------------------------------------------
// Pre-kernel (unchanged from R4, verified): K, V fp32 -> bf16 in 32x32x16-MFMA
// fragment order; both arrays staged through LDS with coalesced float4 reads.
//   Per 64x64 tile, 8 fragments (f) of 64 lanes x 16 B:
//   K frag f=(nt*4+ks), lane l: K[nt*32+(l&31)][ks*16+(l>>5)*8 ..+7]
//   V frag f=(dt*4+ts), lane l: V^T[dt*32+(l&31)][ts*16+(l>>5)*8 ..+7]
// ---------------------------------------------------------------------------
__global__ __launch_bounds__(256)
void cvt(const float* __restrict__ K, const float* __restrict__ V,
         short* __restrict__ Kf, short* __restrict__ Vf) {
    __shared__ short Kl[64][LDP];
    __shared__ short Vl[64][LDP];
    const int tid  = threadIdx.x;
    const int tile = blockIdx.x;
    const int bh   = blockIdx.y;
    const int t0   = tile * 64;

    {   // stage K and V tiles into LDS bf16, coalesced fp32 reads
        const int r = tid >> 2, c = (tid & 3) * 16;
        const float* kp = K + (size_t)(t0 + r) * SROW + bh * D + c;
        const float* vp = V + (size_t)(t0 + r) * SROW + bh * D + c;
        int ok[8], ov[8];
        #pragma unroll
        for (int i = 0; i < 8; ++i) {
            ok[i] = pack2(kp[2 * i], kp[2 * i + 1]);
            ov[i] = pack2(vp[2 * i], vp[2 * i + 1]);
        }
        *(int4*)&Kl[r][c]     = *(int4*)&ok[0];
        *(int4*)&Kl[r][c + 8] = *(int4*)&ok[4];
        *(int4*)&Vl[r][c]     = *(int4*)&ov[0];
        *(int4*)&Vl[r][c + 8] = *(int4*)&ov[4];
    }
    __syncthreads();

    short* kout = Kf + (size_t)bh * PLANE + (size_t)tile * TCH;
    short* vout = Vf + (size_t)bh * PLANE + (size_t)tile * TCH;
    #pragma unroll
    for (int cc = tid; cc < 512; cc += 256) {
        const int f  = cc >> 6, ln = cc & 63, hi = ln >> 5;
        {   // K fragment: aligned b128 LDS read (row stride 144 B)
            const int nt = f >> 2, ks = f & 3;
            const int row = nt * 32 + (ln & 31);
            const int col = ks * 16 + hi * 8;
            *(int4*)&kout[cc * 8] = *(const int4*)&Kl[row][col];
        }
        {   // V^T fragment via LDS transpose gather
            const int dt = f >> 2, ts = f & 3;
            const int d  = dt * 32 + (ln & 31);
            short t8[8];
            #pragma unroll
            for (int j = 0; j < 8; ++j) t8[j] = Vl[ts * 16 + hi * 8 + j][d];
            *(int4*)&vout[cc * 8] = *(int4*)t8;
        }
    }
}

// ---------------------------------------------------------------------------
// Hot kernel v6: 32x32 MFMA causal flash attention, FULLY REGISTER-RESIDENT P.
//  R4 post-mortem: occupancy, fragment bandwidth, and staging pipe were all
//  varied with zero effect; the invariant across all ~48us variants is the
//  per-tile serial chain containing the P LDS round-trip, run by ~1-2
//  waves/SIMD.  This round deletes that round-trip (T12, m214-verified
//  recipe, re-derived for the m101 32x32 D-layout):
//    exp2 -> v_cvt_pk_bf16_f32 (dw[g][c]: t=8g+4h+2c+{0,1})
//         -> v_permlane32_swap_b32(dw[2ts][c], dw[2ts+1][c])
//              = pa[ts] words (w_c, w_{c+2})  [dst.hi31 <-> src.lo31]
//  pa[] feeds the PV MFMA A-operand directly; attn_fwd now uses NO LDS.
//  + T5 s_setprio(1) around MFMA clusters (attn +4-7%, m191; barrier-free
//  independent blocks = the regime where wave arbitration pays).
//  Everything else is the measured v5 config (grid 512, {15-u,u} pairing,
//  bh%8=XCD, L1 fragment reads, mask, epilogue) for clean attribution.
// ---------------------------------------------------------------------------
__global__ __launch_bounds__(256, 2)
void attn_fwd(const float* __restrict__ Q, const short* __restrict__ Kf,
              const short* __restrict__ Vf, float* __restrict__ Out) {
    const int tid  = threadIdx.x;
    const int wave = tid >> 6;
    const int lane = tid & 63;
    const int q32  = lane & 31;
    const int hi   = lane >> 5;

    const int c  = blockIdx.x & 255;
    const int g  = blockIdx.x >> 8;
    const int u  = c >> 5;              // 0..7
    const int bh = c & 31;
    const int a  = g ? u : (15 - u);    // strip128 id, long strips first
    const int s  = 2 * a + (wave >> 1); // last tile index for this wave
    const int limit = 32 * (wave & 1) + q32;  // causal t-limit in diag tile

    const short* kb = Kf + (size_t)bh * PLANE;
    const short* vb = Vf + (size_t)bh * PLANE;
    auto ldK = [&](int t, int f) -> bf16x8 {
        return *(const bf16x8*)(kb + (size_t)t * TCH + f * 512 + lane * 8);
    };
    auto ldV = [&](int t, int f) -> bf16x8 {
        return *(const bf16x8*)(vb + (size_t)t * TCH + f * 512 + lane * 8);
    };

    // prologue: fragments for tile 0
    bf16x8 kf[8], vf[8];
    #pragma unroll
    for (int j = 0; j < 8; ++j) { kf[j] = ldK(0, j); vf[j] = ldV(0, j); }

    // ---- Q B-fragments: lane holds Q[qrow][ks*16 + hi*8 ..+7], scaled ----
    bf16x8 qf[4];
    {
        const int qrow = a * 128 + wave * 32 + q32;
        const float* qp = Q + (size_t)qrow * SROW + bh * D + hi * 8;
        #pragma unroll
        for (int ks = 0; ks < 4; ++ks) {
            float4 x0 = *(const float4*)(qp + ks * 16);
            float4 x1 = *(const float4*)(qp + ks * 16 + 4);
            int o4[4];
            o4[0] = pack2(x0.x * QSCALE, x0.y * QSCALE);
            o4[1] = pack2(x0.z * QSCALE, x0.w * QSCALE);
            o4[2] = pack2(x1.x * QSCALE, x1.y * QSCALE);
            o4[3] = pack2(x1.z * QSCALE, x1.w * QSCALE);
            qf[ks] = *(bf16x8*)o4;
        }
    }

    f32x16 o0 = z16(), o1 = z16(), l = z16();
    bf16x8 ones;
    #pragma unroll
    for (int i = 0; i < 8; ++i) ones[i] = (short)0x3F80;  // bf16 1.0

    for (int it = 0; it <= s; ++it) {
        // ---- S^T = K Q^T (two 32x32 t-tiles, K-dim 64 in 4 steps) ----
        f32x16 sA = z16(), sB = z16();
        __builtin_amdgcn_s_setprio(1);
        #pragma unroll
        for (int ks = 0; ks < 4; ++ks)
            sA = __builtin_amdgcn_mfma_f32_32x32x16_bf16(kf[ks],     qf[ks], sA, 0, 0, 0);
        #pragma unroll
        for (int ks = 0; ks < 4; ++ks)
            sB = __builtin_amdgcn_mfma_f32_32x32x16_bf16(kf[4 + ks], qf[ks], sB, 0, 0, 0);
        __builtin_amdgcn_s_setprio(0);

        // ---- prefetch K fragments for next tile (clamped, branchless) ----
        const int nx = (it < s) ? it + 1 : s;
        #pragma unroll
        for (int j = 0; j < 8; ++j) kf[j] = ldK(nx, j);

        // ---- exp2 + cvt_pk + permlane32_swap -> PA fragments, in-register ----
        // dw[g][c] holds t = 8g+4*hi+2c+{0,1}; swap(dw[2ts][c], dw[2ts+1][c])
        // -> pa[ts] dwords (w_c, w_{c+2})   [T12 / m214-verified mapping]
        const bool diag = (it == s);
        bf16x8 pa[4];
        #pragma unroll
        for (int nt = 0; nt < 2; ++nt) {
            const f32x16& sN = nt ? sB : sA;
            float e[16];
            #pragma unroll
            for (int r = 0; r < 16; ++r) {
                const int tl = nt * 32 + (r & 3) + 8 * (r >> 2) + 4 * hi;
                float xv = sN[r];
                if (diag && tl > limit) xv = -1e30f;
                e[r] = __builtin_exp2f(xv);
            }
            int dw[8];
            #pragma unroll
            for (int i = 0; i < 8; ++i)
                asm("v_cvt_pk_bf16_f32 %0, %1, %2"
                    : "=v"(dw[i]) : "v"(e[2 * i]), "v"(e[2 * i + 1]));
            #pragma unroll
            for (int half = 0; half < 2; ++half) {
                int a0 = dw[4 * half + 0], b0 = dw[4 * half + 2];  // c=0 pair
                int a1 = dw[4 * half + 1], b1 = dw[4 * half + 3];  // c=1 pair
                asm("v_permlane32_swap_b32 %0, %1" : "+v"(a0), "+v"(b0));
                asm("v_permlane32_swap_b32 %0, %1" : "+v"(a1), "+v"(b1));
                int4 w = make_int4(a0, a1, b0, b1);   // {w0,w1,w2,w3}
                pa[nt * 2 + half] = *(bf16x8*)&w;
            }
        }

        // ---- O += P V ; l += P*1 (pa = A-operand, straight from regs) ----
        __builtin_amdgcn_s_setprio(1);
        #pragma unroll
        for (int ts = 0; ts < 4; ++ts) {
            l  = __builtin_amdgcn_mfma_f32_32x32x16_bf16(pa[ts], ones,       l,  0, 0, 0);
            o0 = __builtin_amdgcn_mfma_f32_32x32x16_bf16(pa[ts], vf[ts],     o0, 0, 0, 0);
            o1 = __builtin_amdgcn_mfma_f32_32x32x16_bf16(pa[ts], vf[4 + ts], o1, 0, 0, 0);
        }
        __builtin_amdgcn_s_setprio(0);

        // ---- prefetch V fragments for next tile ----
        #pragma unroll
        for (int j = 0; j < 8; ++j) vf[j] = ldV(nx, j);
    }

    // ---- epilogue: normalize, store fp32 (lane = one d column, 16 q rows) ----
    #pragma unroll
    for (int r = 0; r < 16; ++r) {
        const int qr   = (r & 3) + 8 * (r >> 2) + 4 * hi;
        const float inv = 1.f / l[r];
        float* op = Out + (size_t)(a * 128 + wave * 32 + qr) * SROW + bh * D;
        op[q32]      = o0[r] * inv;
        op[32 + q32] = o1[r] * inv;
    }
}

extern "C" void kernel_launch(void* const* d_in, const int* in_sizes, int n_in,
                              void* d_out, int out_size, void* d_ws, size_t ws_size,
                              hipStream_t stream) {
    const float* Q = (const float*)d_in[0];
    const float* K = (const float*)d_in[1];
    const float* V = (const float*)d_in[2];
    // d_in[3] (attention_mask) is pure causal — folded into the kernel.
    float* Out = (float*)d_out;

    // d_ws layout: Kf | Vf (bf16, fragment order), 8 MB each
    short* Kf = (short*)d_ws;
    short* Vf = Kf + (size_t)BH * PLANE;

    dim3 gcvt(SQ / 64, BH);
    cvt<<<gcvt, 256, 0, stream>>>(K, V, Kf, Vf);
    attn_fwd<<<dim3(512), 256, 0, stream>>>(Q, Kf, Vf, Out);
}